// Round 1
// baseline (1021.646 us; speedup 1.0000x reference)
//
#include <hip/hip_runtime.h>
#include <hip/hip_bf16.h>
#include <stdint.h>

// ---------------- problem constants ----------------
constexpr int NT = 8192;   // tokens (B*S)
constexpr int NE = 8;      // experts
constexpr int ND = 1024;   // d_model
constexpr int NH = 4096;   // hidden

typedef __attribute__((ext_vector_type(8))) short short8;  // 8 bf16 (4 VGPRs)
typedef __attribute__((ext_vector_type(4))) float f32x4;

// ---------------- workspace layout (bytes) ----------------
constexpr size_t O_XBF  = 0;                                   // x bf16 [NT][ND]
constexpr size_t O_WUPT = O_XBF  + (size_t)NT * ND * 2;        // w_up^T bf16 [E][H][D]
constexpr size_t O_WDNT = O_WUPT + (size_t)NE * NH * ND * 2;   // w_down^T bf16 [E][D][H]
constexpr size_t O_HBUF = O_WDNT + (size_t)NE * ND * NH * 2;   // hidden bf16 [NT*2][NH]
constexpr size_t O_STOK = O_HBUF + (size_t)NT * 2 * NH * 2;    // slot -> token
constexpr size_t O_SP   = O_STOK + (size_t)NT * 2 * 4;         // slot -> gate p
constexpr size_t O_TKE  = O_SP   + (size_t)NT * 2 * 4;         // token -> top2 experts
constexpr size_t O_TKP  = O_TKE  + (size_t)NT * 2 * 4;         // token -> top2 probs
constexpr size_t O_CTRL = O_TKP  + (size_t)NT * 2 * 4;         // cnt[16]@0 fill[16]@64 probsum[8]@128 off[16]@192
// total = O_CTRL + 256  (~272 MiB)

__device__ __forceinline__ void gl_lds16(const void* g, void* l) {
  using GP = char __attribute__((address_space(1))) *;
  using LP = char __attribute__((address_space(3))) *;
  __builtin_amdgcn_global_load_lds((GP)(uintptr_t)g, (LP)(uint32_t)(uintptr_t)l, 16, 0, 0);
}

__device__ __forceinline__ float fast_gelu(float x) {
  // tanh-approx gelu (jax.nn.gelu default), tanh via exp
  float u  = 0.7978845608028654f * (x + 0.044715f * x * x * x);
  float ex = __expf(2.0f * u);
  float th = 1.0f - 2.0f / (ex + 1.0f);
  return 0.5f * x * (1.0f + th);
}

// ---------------- router: logits, softmax, top2, counts; also x->bf16 ----------------
__global__ __launch_bounds__(256) void moe_router(
    const float* __restrict__ x, const float* __restrict__ rw, const float* __restrict__ rb,
    __hip_bfloat16* __restrict__ xbf,
    float* __restrict__ probs_out, int* __restrict__ topk_e, float* __restrict__ topk_p,
    int* __restrict__ cnt_ek, float* __restrict__ probsum)
{
  __shared__ float ps[NE];
  __shared__ int cs[16];
  const int tid = threadIdx.x;
  if (tid < NE) ps[tid] = 0.f;
  if (tid < 16) cs[tid] = 0;
  __syncthreads();
  const int lane = tid & 63, wv = tid >> 6;
  for (int it = 0; it < 8; ++it) {
    const int t = blockIdx.x * 4 + wv + it * 1024;   // 256 blocks * 4 waves * 8 iters = 8192
    const float* xr = x + (size_t)t * ND;
    float acc[NE] = {};
#pragma unroll 4
    for (int j = 0; j < 16; ++j) {
      const int d = j * 64 + lane;
      const float xv = xr[d];
      xbf[(size_t)t * ND + d] = __float2bfloat16(xv);
      const float* w = rw + (size_t)d * NE;
#pragma unroll
      for (int ee = 0; ee < NE; ++ee) acc[ee] += xv * w[ee];
    }
#pragma unroll
    for (int ee = 0; ee < NE; ++ee)
#pragma unroll
      for (int off = 32; off >= 1; off >>= 1)
        acc[ee] += __shfl_down(acc[ee], off, 64);
    if (lane == 0) {
      float lg[NE];
#pragma unroll
      for (int ee = 0; ee < NE; ++ee) lg[ee] = acc[ee] + rb[ee];
      float mx = lg[0];
#pragma unroll
      for (int ee = 1; ee < NE; ++ee) mx = fmaxf(mx, lg[ee]);
      float s = 0.f, pe[NE];
#pragma unroll
      for (int ee = 0; ee < NE; ++ee) { pe[ee] = __expf(lg[ee] - mx); s += pe[ee]; }
      const float inv = 1.f / s;
#pragma unroll
      for (int ee = 0; ee < NE; ++ee) {
        const float pr = pe[ee] * inv;
        probs_out[(size_t)t * NE + ee] = pr;
        atomicAdd(&ps[ee], pr);
      }
      int i1 = 0; float l1 = lg[0];
#pragma unroll
      for (int ee = 1; ee < NE; ++ee) if (lg[ee] > l1) { l1 = lg[ee]; i1 = ee; }
      int i2 = 0; float l2 = -3.0e38f;
#pragma unroll
      for (int ee = 0; ee < NE; ++ee) if (ee != i1 && lg[ee] > l2) { l2 = lg[ee]; i2 = ee; }
      const float e2 = __expf(l2 - l1);
      const float dn = 1.f + e2;
      topk_e[t * 2]     = i1;  topk_e[t * 2 + 1] = i2;
      topk_p[t * 2]     = 1.f / dn;
      topk_p[t * 2 + 1] = e2 / dn;
      atomicAdd(&cs[i1 * 2], 1);
      atomicAdd(&cs[i2 * 2 + 1], 1);
    }
  }
  __syncthreads();
  if (tid < NE) atomicAdd(&probsum[tid], ps[tid]);
  if (tid < 16) atomicAdd(&cnt_ek[tid], cs[tid]);
}

// ---------------- offsets prefix + aux loss ----------------
__global__ void moe_finalize(const int* __restrict__ cnt_ek, int* __restrict__ off_ek,
                             const float* __restrict__ probsum, float* __restrict__ aux_out)
{
  if (threadIdx.x == 0 && blockIdx.x == 0) {
    int run = 0;
    for (int i = 0; i < 16; ++i) { off_ek[i] = run; run += cnt_ek[i]; }
    float aux = 0.f;
    for (int ee = 0; ee < NE; ++ee) {
      float frac = (float)(cnt_ek[2 * ee] + cnt_ek[2 * ee + 1]) / (float)(NT * 2);
      aux += frac * (probsum[ee] / (float)NT);
    }
    aux_out[0] = (float)NE * aux * 0.01f;
  }
}

// ---------------- scatter tokens into (expert,k) buckets ----------------
__global__ __launch_bounds__(256) void moe_scatter(
    const int* __restrict__ topk_e, const float* __restrict__ topk_p,
    const int* __restrict__ off_ek, int* __restrict__ fill_ek,
    int* __restrict__ slot_token, float* __restrict__ slot_p)
{
  const int t = blockIdx.x * 256 + threadIdx.x;
  if (t >= NT) return;
#pragma unroll
  for (int k = 0; k < 2; ++k) {
    const int ee = topk_e[t * 2 + k];
    const int id = ee * 2 + k;
    const int r = atomicAdd(&fill_ek[id], 1);
    const int slot = off_ek[id] + r;
    slot_token[slot] = t;
    slot_p[slot] = topk_p[t * 2 + k];
  }
}

// ---------------- transpose+cast: in fp32 [E][A][B] -> out bf16 [E][B][A] ----------------
__global__ __launch_bounds__(256) void moe_transpose_cast(
    const float* __restrict__ in, __hip_bfloat16* __restrict__ outp, int Adim, int Bdim)
{
  __shared__ float tile[64][65];
  const int e = blockIdx.z;
  const int b0 = blockIdx.x * 64, a0 = blockIdx.y * 64;
  const float* ip = in + (size_t)e * Adim * Bdim + (size_t)a0 * Bdim + b0;
  const int c = threadIdx.x & 63, r4 = threadIdx.x >> 6;
#pragma unroll
  for (int i = 0; i < 16; ++i) {
    const int r = r4 * 16 + i;
    tile[r][c] = ip[(size_t)r * Bdim + c];
  }
  __syncthreads();
  __hip_bfloat16* op = outp + (size_t)e * Bdim * Adim + (size_t)b0 * Adim + a0;
  const int rr = threadIdx.x & 63, c4 = threadIdx.x >> 6;
#pragma unroll
  for (int i = 0; i < 16; ++i) {
    const int cc = c4 * 16 + i;
    op[(size_t)cc * Adim + rr] = __float2bfloat16(tile[rr][cc]);
  }
}

// ---------------- grouped GEMM 1: H = gelu(X_sel @ w_up + b_up) ----------------
// 128x128 tile, 4 waves (2x2 of 64x64), 16x16x32 bf16 MFMA, BK=32.
// LDS chunk swizzle: lds slot (row, kc) holds global k-chunk kc ^ ((row>>1)&3).
__global__ __launch_bounds__(256, 2) void moe_gemm_up(
    const __hip_bfloat16* __restrict__ xbf,
    const __hip_bfloat16* __restrict__ wupT,   // [E][H][D]
    const float* __restrict__ b_up,
    const int* __restrict__ slot_token,
    const int* __restrict__ cnt_ek, const int* __restrict__ off_ek,
    __hip_bfloat16* __restrict__ hbuf)          // [NT*2][NH]
{
  const int e = blockIdx.z;
  const int cnt = cnt_ek[2 * e] + cnt_ek[2 * e + 1];
  const int m0 = blockIdx.y * 128;
  if (m0 >= cnt) return;
  const int base = off_ek[2 * e];
  const int n0 = blockIdx.x * 128;
  const int valid = (cnt - m0 < 128) ? (cnt - m0) : 128;

  __shared__ __align__(16) __hip_bfloat16 As[128 * 32];
  __shared__ __align__(16) __hip_bfloat16 Bs[128 * 32];

  const int tid = threadIdx.x;
  const int lane = tid & 63, wv = tid >> 6;

  // staging: 512 16B-chunks per tile, 2 per thread per buffer
  const int c0 = tid, c1 = 256 + tid;
  const int ra0 = c0 >> 2, ra1 = c1 >> 2;
  const int kc0 = (((c0 & 3) ^ ((ra0 >> 1) & 3))) * 8;
  const int kc1 = (((c1 & 3) ^ ((ra1 >> 1) & 3))) * 8;
  const int sa0 = base + ((m0 + ra0 < cnt) ? (m0 + ra0) : (cnt - 1));
  const int sa1 = base + ((m0 + ra1 < cnt) ? (m0 + ra1) : (cnt - 1));
  const __hip_bfloat16* ga0 = xbf + (size_t)slot_token[sa0] * ND + kc0;
  const __hip_bfloat16* ga1 = xbf + (size_t)slot_token[sa1] * ND + kc1;
  const __hip_bfloat16* gb0 = wupT + ((size_t)e * NH + n0 + ra0) * ND + kc0;
  const __hip_bfloat16* gb1 = wupT + ((size_t)e * NH + n0 + ra1) * ND + kc1;
  char* lA0 = (char*)As + c0 * 16;  char* lA1 = (char*)As + c1 * 16;
  char* lB0 = (char*)Bs + c0 * 16;  char* lB1 = (char*)Bs + c1 * 16;

  const int wm = (wv >> 1) * 64, wn = (wv & 1) * 64;
  const int l15 = lane & 15, q = lane >> 4;
  const int ssw = (q ^ ((l15 >> 1) & 3)) * 16;
  const char* rA = (const char*)As + (wm + l15) * 64 + ssw;
  const char* rB = (const char*)Bs + (wn + l15) * 64 + ssw;

  f32x4 acc[4][4] = {};

  for (int kk = 0; kk < ND; kk += 32) {
    __syncthreads();
    gl_lds16(ga0 + kk, lA0);
    gl_lds16(ga1 + kk, lA1);
    gl_lds16(gb0 + kk, lB0);
    gl_lds16(gb1 + kk, lB1);
    __syncthreads();
    short8 af[4], bfr[4];
#pragma unroll
    for (int i = 0; i < 4; ++i) af[i]  = *(const short8*)(rA + i * 1024);
#pragma unroll
    for (int i = 0; i < 4; ++i) bfr[i] = *(const short8*)(rB + i * 1024);
#pragma unroll
    for (int mt = 0; mt < 4; ++mt)
#pragma unroll
      for (int nt = 0; nt < 4; ++nt)
        acc[mt][nt] = __builtin_amdgcn_mfma_f32_16x16x32_bf16(af[mt], bfr[nt], acc[mt][nt], 0, 0, 0);
  }

#pragma unroll
  for (int mt = 0; mt < 4; ++mt) {
#pragma unroll
    for (int rr = 0; rr < 4; ++rr) {
      const int row = wm + mt * 16 + q * 4 + rr;
      if (row < valid) {
        const size_t rbase = (size_t)(base + m0 + row) * NH;
#pragma unroll
        for (int nt = 0; nt < 4; ++nt) {
          const int col = n0 + wn + nt * 16 + l15;
          const float v = acc[mt][nt][rr] + b_up[e * NH + col];
          hbuf[rbase + col] = __float2bfloat16(fast_gelu(v));
        }
      }
    }
  }
}

// ---------------- grouped GEMM 2: out += p * (H @ w_down + b_down) ----------------
// kpos selects the (expert, k) buckets: each token appears exactly once per launch,
// so kpos=0 plain-stores and kpos=1 RMW-adds -- no atomics needed.
__global__ __launch_bounds__(256, 2) void moe_gemm_down(
    const __hip_bfloat16* __restrict__ hbuf,
    const __hip_bfloat16* __restrict__ wdnT,   // [E][D][H]
    const float* __restrict__ b_down,
    const int* __restrict__ slot_token, const float* __restrict__ slot_p,
    const int* __restrict__ cnt_ek, const int* __restrict__ off_ek,
    float* __restrict__ out, int kpos)
{
  const int e = blockIdx.z;
  const int id = 2 * e + kpos;
  const int cnt = cnt_ek[id];
  const int m0 = blockIdx.y * 128;
  if (m0 >= cnt) return;
  const int base = off_ek[id];
  const int n0 = blockIdx.x * 128;
  const int valid = (cnt - m0 < 128) ? (cnt - m0) : 128;

  __shared__ __align__(16) __hip_bfloat16 As[128 * 32];
  __shared__ __align__(16) __hip_bfloat16 Bs[128 * 32];

  const int tid = threadIdx.x;
  const int lane = tid & 63, wv = tid >> 6;

  const int c0 = tid, c1 = 256 + tid;
  const int ra0 = c0 >> 2, ra1 = c1 >> 2;
  const int kc0 = (((c0 & 3) ^ ((ra0 >> 1) & 3))) * 8;
  const int kc1 = (((c1 & 3) ^ ((ra1 >> 1) & 3))) * 8;
  const int sa0 = base + ((m0 + ra0 < cnt) ? (m0 + ra0) : (cnt - 1));
  const int sa1 = base + ((m0 + ra1 < cnt) ? (m0 + ra1) : (cnt - 1));
  const __hip_bfloat16* ga0 = hbuf + (size_t)sa0 * NH + kc0;
  const __hip_bfloat16* ga1 = hbuf + (size_t)sa1 * NH + kc1;
  const __hip_bfloat16* gb0 = wdnT + ((size_t)e * ND + n0 + ra0) * NH + kc0;
  const __hip_bfloat16* gb1 = wdnT + ((size_t)e * ND + n0 + ra1) * NH + kc1;
  char* lA0 = (char*)As + c0 * 16;  char* lA1 = (char*)As + c1 * 16;
  char* lB0 = (char*)Bs + c0 * 16;  char* lB1 = (char*)Bs + c1 * 16;

  const int wm = (wv >> 1) * 64, wn = (wv & 1) * 64;
  const int l15 = lane & 15, q = lane >> 4;
  const int ssw = (q ^ ((l15 >> 1) & 3)) * 16;
  const char* rA = (const char*)As + (wm + l15) * 64 + ssw;
  const char* rB = (const char*)Bs + (wn + l15) * 64 + ssw;

  f32x4 acc[4][4] = {};

  for (int kk = 0; kk < NH; kk += 32) {
    __syncthreads();
    gl_lds16(ga0 + kk, lA0);
    gl_lds16(ga1 + kk, lA1);
    gl_lds16(gb0 + kk, lB0);
    gl_lds16(gb1 + kk, lB1);
    __syncthreads();
    short8 af[4], bfr[4];
#pragma unroll
    for (int i = 0; i < 4; ++i) af[i]  = *(const short8*)(rA + i * 1024);
#pragma unroll
    for (int i = 0; i < 4; ++i) bfr[i] = *(const short8*)(rB + i * 1024);
#pragma unroll
    for (int mt = 0; mt < 4; ++mt)
#pragma unroll
      for (int nt = 0; nt < 4; ++nt)
        acc[mt][nt] = __builtin_amdgcn_mfma_f32_16x16x32_bf16(af[mt], bfr[nt], acc[mt][nt], 0, 0, 0);
  }

#pragma unroll
  for (int mt = 0; mt < 4; ++mt) {
#pragma unroll
    for (int rr = 0; rr < 4; ++rr) {
      const int row = wm + mt * 16 + q * 4 + rr;
      if (row < valid) {
        const int slot = base + m0 + row;
        const int tok = slot_token[slot];
        const float p = slot_p[slot];
        const size_t obase = (size_t)tok * ND;
#pragma unroll
        for (int nt = 0; nt < 4; ++nt) {
          const int col = n0 + wn + nt * 16 + l15;
          const float v = (acc[mt][nt][rr] + b_down[e * ND + col]) * p;
          if (kpos == 0) out[obase + col] = v;
          else           out[obase + col] += v;
        }
      }
    }
  }
}

// ---------------- launch ----------------
extern "C" void kernel_launch(void* const* d_in, const int* in_sizes, int n_in,
                              void* d_out, int out_size, void* d_ws, size_t ws_size,
                              hipStream_t stream) {
  (void)in_sizes; (void)n_in; (void)out_size; (void)ws_size;
  const float* x   = (const float*)d_in[0];
  const float* rw  = (const float*)d_in[1];
  const float* rb  = (const float*)d_in[2];
  const float* wup = (const float*)d_in[3];
  const float* bup = (const float*)d_in[4];
  const float* wdn = (const float*)d_in[5];
  const float* bdn = (const float*)d_in[6];
  float* out = (float*)d_out;

  char* ws = (char*)d_ws;
  __hip_bfloat16* xbf  = (__hip_bfloat16*)(ws + O_XBF);
  __hip_bfloat16* wupT = (__hip_bfloat16*)(ws + O_WUPT);
  __hip_bfloat16* wdnT = (__hip_bfloat16*)(ws + O_WDNT);
  __hip_bfloat16* hbuf = (__hip_bfloat16*)(ws + O_HBUF);
  int*   slot_token = (int*)(ws + O_STOK);
  float* slot_p     = (float*)(ws + O_SP);
  int*   topk_e     = (int*)(ws + O_TKE);
  float* topk_p     = (float*)(ws + O_TKP);
  int*   cnt_ek  = (int*)(ws + O_CTRL);
  int*   fill_ek = (int*)(ws + O_CTRL + 64);
  float* probsum = (float*)(ws + O_CTRL + 128);
  int*   off_ek  = (int*)(ws + O_CTRL + 192);

  hipMemsetAsync(ws + O_CTRL, 0, 256, stream);

  // weight transposes (independent of router)
  moe_transpose_cast<<<dim3(NH / 64, ND / 64, NE), 256, 0, stream>>>(wup, wupT, ND, NH);
  moe_transpose_cast<<<dim3(ND / 64, NH / 64, NE), 256, 0, stream>>>(wdn, wdnT, NH, ND);

  // router (+ x->bf16), aux/offsets, scatter
  moe_router<<<256, 256, 0, stream>>>(x, rw, rb, xbf, out + (size_t)NT * ND + 1,
                                      topk_e, topk_p, cnt_ek, probsum);
  moe_finalize<<<1, 64, 0, stream>>>(cnt_ek, off_ek, probsum, out + (size_t)NT * ND);
  moe_scatter<<<NT / 256, 256, 0, stream>>>(topk_e, topk_p, off_ek, fill_ek, slot_token, slot_p);

  // grouped GEMMs (worst-case grids; blocks early-exit past device-side counts)
  moe_gemm_up<<<dim3(NH / 128, 64, NE), 256, 0, stream>>>(xbf, wupT, bup, slot_token,
                                                          cnt_ek, off_ek, hbuf);
  moe_gemm_down<<<dim3(ND / 128, 64, NE), 256, 0, stream>>>(hbuf, wdnT, bdn, slot_token, slot_p,
                                                            cnt_ek, off_ek, out, 0);
  moe_gemm_down<<<dim3(ND / 128, 64, NE), 256, 0, stream>>>(hbuf, wdnT, bdn, slot_token, slot_p,
                                                            cnt_ek, off_ek, out, 1);
}

// Round 2
// 933.181 us; speedup vs baseline: 1.0948x; 1.0948x over previous
//
#include <hip/hip_runtime.h>
#include <hip/hip_bf16.h>
#include <stdint.h>

// ---------------- problem constants ----------------
constexpr int NT = 8192;   // tokens (B*S)
constexpr int NE = 8;      // experts
constexpr int ND = 1024;   // d_model
constexpr int NH = 4096;   // hidden

typedef __attribute__((ext_vector_type(8))) short short8;  // 8 bf16 (4 VGPRs)
typedef __attribute__((ext_vector_type(4))) float f32x4;

// ---------------- workspace layout (bytes) ----------------
constexpr size_t O_XBF  = 0;                                   // x bf16 [NT][ND]
constexpr size_t O_WUPT = O_XBF  + (size_t)NT * ND * 2;        // w_up^T bf16 [E][H][D]
constexpr size_t O_WDNT = O_WUPT + (size_t)NE * NH * ND * 2;   // w_down^T bf16 [E][D][H]
constexpr size_t O_HBUF = O_WDNT + (size_t)NE * ND * NH * 2;   // hidden bf16 [NT*2][NH]
constexpr size_t O_STOK = O_HBUF + (size_t)NT * 2 * NH * 2;    // slot -> token
constexpr size_t O_SP   = O_STOK + (size_t)NT * 2 * 4;         // slot -> gate p
constexpr size_t O_TKE  = O_SP   + (size_t)NT * 2 * 4;         // token -> top2 experts
constexpr size_t O_TKP  = O_TKE  + (size_t)NT * 2 * 4;         // token -> top2 probs
constexpr size_t O_CTRL = O_TKP  + (size_t)NT * 2 * 4;
// ctrl: cnt[16]@0 fill[16]@64 probsum[8]@128 off[16]@192, ntu@256, ntd0@260, ntd1@264
constexpr size_t O_TLUP = O_CTRL + 272;                        // int[144] tile list up
constexpr size_t O_TLDN = O_TLUP + 144 * 4;                    // int[2][80] tile list down

__device__ __forceinline__ void gl_lds16(const void* g, void* l) {
  using GP = char __attribute__((address_space(1))) *;
  using LP = char __attribute__((address_space(3))) *;
  __builtin_amdgcn_global_load_lds((GP)(uintptr_t)g, (LP)(uint32_t)(uintptr_t)l, 16, 0, 0);
}

__device__ __forceinline__ float fast_gelu(float x) {
  float u  = 0.7978845608028654f * (x + 0.044715f * x * x * x);
  float ex = __expf(2.0f * u);
  float th = 1.0f - 2.0f / (ex + 1.0f);
  return 0.5f * x * (1.0f + th);
}

// ---------------- router: logits, softmax, top2, counts; also x->bf16 ----------------
__global__ __launch_bounds__(256) void moe_router(
    const float* __restrict__ x, const float* __restrict__ rw, const float* __restrict__ rb,
    __hip_bfloat16* __restrict__ xbf,
    float* __restrict__ probs_out, int* __restrict__ topk_e, float* __restrict__ topk_p,
    int* __restrict__ cnt_ek, float* __restrict__ probsum)
{
  __shared__ float ps[NE];
  __shared__ int cs[16];
  const int tid = threadIdx.x;
  if (tid < NE) ps[tid] = 0.f;
  if (tid < 16) cs[tid] = 0;
  __syncthreads();
  const int lane = tid & 63, wv = tid >> 6;
  for (int it = 0; it < 8; ++it) {
    const int t = blockIdx.x * 4 + wv + it * 1024;
    const float* xr = x + (size_t)t * ND;
    float acc[NE] = {};
#pragma unroll 4
    for (int j = 0; j < 16; ++j) {
      const int d = j * 64 + lane;
      const float xv = xr[d];
      xbf[(size_t)t * ND + d] = __float2bfloat16(xv);
      const float* w = rw + (size_t)d * NE;
#pragma unroll
      for (int ee = 0; ee < NE; ++ee) acc[ee] += xv * w[ee];
    }
#pragma unroll
    for (int ee = 0; ee < NE; ++ee)
#pragma unroll
      for (int off = 32; off >= 1; off >>= 1)
        acc[ee] += __shfl_down(acc[ee], off, 64);
    if (lane == 0) {
      float lg[NE];
#pragma unroll
      for (int ee = 0; ee < NE; ++ee) lg[ee] = acc[ee] + rb[ee];
      float mx = lg[0];
#pragma unroll
      for (int ee = 1; ee < NE; ++ee) mx = fmaxf(mx, lg[ee]);
      float s = 0.f, pe[NE];
#pragma unroll
      for (int ee = 0; ee < NE; ++ee) { pe[ee] = __expf(lg[ee] - mx); s += pe[ee]; }
      const float inv = 1.f / s;
#pragma unroll
      for (int ee = 0; ee < NE; ++ee) {
        const float pr = pe[ee] * inv;
        probs_out[(size_t)t * NE + ee] = pr;
        atomicAdd(&ps[ee], pr);
      }
      int i1 = 0; float l1 = lg[0];
#pragma unroll
      for (int ee = 1; ee < NE; ++ee) if (lg[ee] > l1) { l1 = lg[ee]; i1 = ee; }
      int i2 = 0; float l2 = -3.0e38f;
#pragma unroll
      for (int ee = 0; ee < NE; ++ee) if (ee != i1 && lg[ee] > l2) { l2 = lg[ee]; i2 = ee; }
      const float e2 = __expf(l2 - l1);
      const float dn = 1.f + e2;
      topk_e[t * 2]     = i1;  topk_e[t * 2 + 1] = i2;
      topk_p[t * 2]     = 1.f / dn;
      topk_p[t * 2 + 1] = e2 / dn;
      atomicAdd(&cs[i1 * 2], 1);
      atomicAdd(&cs[i2 * 2 + 1], 1);
    }
  }
  __syncthreads();
  if (tid < NE) atomicAdd(&probsum[tid], ps[tid]);
  if (tid < 16) atomicAdd(&cnt_ek[tid], cs[tid]);
}

// ---------------- offsets prefix + aux loss + tile lists ----------------
__global__ void moe_finalize(const int* __restrict__ cnt_ek, int* __restrict__ off_ek,
                             const float* __restrict__ probsum, float* __restrict__ aux_out,
                             int* __restrict__ ntiles, int* __restrict__ tl_up,
                             int* __restrict__ tl_dn)
{
  if (threadIdx.x == 0 && blockIdx.x == 0) {
    int run = 0;
    for (int i = 0; i < 16; ++i) { off_ek[i] = run; run += cnt_ek[i]; }
    float aux = 0.f;
    for (int ee = 0; ee < NE; ++ee) {
      float frac = (float)(cnt_ek[2 * ee] + cnt_ek[2 * ee + 1]) / (float)(NT * 2);
      aux += frac * (probsum[ee] / (float)NT);
    }
    aux_out[0] = (float)NE * aux * 0.01f;
    // tile lists: (e<<16)|m_block
    int ntu = 0;
    for (int e = 0; e < NE; ++e) {
      const int c = cnt_ek[2 * e] + cnt_ek[2 * e + 1];
      for (int mb = 0; mb < (c + 127) / 128; ++mb) tl_up[ntu++] = (e << 16) | mb;
    }
    ntiles[0] = ntu;
    for (int kp = 0; kp < 2; ++kp) {
      int nt = 0;
      for (int e = 0; e < NE; ++e) {
        const int c = cnt_ek[2 * e + kp];
        for (int mb = 0; mb < (c + 127) / 128; ++mb) tl_dn[kp * 80 + nt++] = (e << 16) | mb;
      }
      ntiles[1 + kp] = nt;
    }
  }
}

// ---------------- scatter tokens into (expert,k) buckets ----------------
__global__ __launch_bounds__(256) void moe_scatter(
    const int* __restrict__ topk_e, const float* __restrict__ topk_p,
    const int* __restrict__ off_ek, int* __restrict__ fill_ek,
    int* __restrict__ slot_token, float* __restrict__ slot_p)
{
  const int t = blockIdx.x * 256 + threadIdx.x;
  if (t >= NT) return;
#pragma unroll
  for (int k = 0; k < 2; ++k) {
    const int ee = topk_e[t * 2 + k];
    const int id = ee * 2 + k;
    const int r = atomicAdd(&fill_ek[id], 1);
    const int slot = off_ek[id] + r;
    slot_token[slot] = t;
    slot_p[slot] = topk_p[t * 2 + k];
  }
}

// ---------------- transpose+cast: in fp32 [E][A][B] -> out bf16 [E][B][A] ----------------
// vectorized: float4 reads, bf16 LDS tile (stride 66), 16B packed stores
__global__ __launch_bounds__(256) void moe_transpose_cast(
    const float* __restrict__ in, __hip_bfloat16* __restrict__ outp, int Adim, int Bdim)
{
  __shared__ unsigned short tile[64 * 66];
  const int e = blockIdx.z;
  const int b0 = blockIdx.x * 64, a0 = blockIdx.y * 64;
  const float* ip = in + (size_t)e * Adim * Bdim + (size_t)a0 * Bdim + b0;
  const int c4 = (threadIdx.x & 15) * 4;   // col group (4 floats)
  const int r0 = threadIdx.x >> 4;         // base row, step 16
#pragma unroll
  for (int i = 0; i < 4; ++i) {
    const int r = r0 + i * 16;
    const float4 v = *(const float4*)(ip + (size_t)r * Bdim + c4);
    ushort4 u;
    u.x = __hip_bfloat16_raw(__float2bfloat16(v.x)).x;
    u.y = __hip_bfloat16_raw(__float2bfloat16(v.y)).x;
    u.z = __hip_bfloat16_raw(__float2bfloat16(v.z)).x;
    u.w = __hip_bfloat16_raw(__float2bfloat16(v.w)).x;
    *(ushort4*)&tile[r * 66 + c4] = u;
  }
  __syncthreads();
  unsigned short* op = (unsigned short*)outp + (size_t)e * Bdim * Adim + (size_t)b0 * Adim + a0;
  const int cc  = threadIdx.x >> 2;        // output row (source col)
  const int rr0 = (threadIdx.x & 3) * 16;  // output col group
  unsigned short u[16];
#pragma unroll
  for (int i = 0; i < 16; ++i) u[i] = tile[(rr0 + i) * 66 + cc];
  *(short8*)(op + (size_t)cc * Adim + rr0)     = *(short8*)&u[0];
  *(short8*)(op + (size_t)cc * Adim + rr0 + 8) = *(short8*)&u[8];
}

// ---------------- grouped GEMM 1: H = gelu(X_sel @ w_up + b_up) ----------------
// 128x128 tile, 8 waves (2m x 4n of 64x32), 16x16x32 bf16 MFMA, BK=32, tile-list grid.
__global__ __launch_bounds__(512, 5) void moe_gemm_up(
    const __hip_bfloat16* __restrict__ xbf,
    const __hip_bfloat16* __restrict__ wupT,   // [E][H][D]
    const float* __restrict__ b_up,
    const int* __restrict__ slot_token,
    const int* __restrict__ cnt_ek, const int* __restrict__ off_ek,
    const int* __restrict__ ntiles, const int* __restrict__ tl_up,
    __hip_bfloat16* __restrict__ hbuf)          // [NT*2][NH]
{
  if ((int)blockIdx.y >= ntiles[0]) return;
  const int tl = tl_up[blockIdx.y];
  const int e = tl >> 16, mb = tl & 0xffff;
  const int cnt = cnt_ek[2 * e] + cnt_ek[2 * e + 1];
  const int base = off_ek[2 * e];
  const int m0 = mb * 128;
  const int n0 = blockIdx.x * 128;
  const int valid = (cnt - m0 < 128) ? (cnt - m0) : 128;

  __shared__ __align__(16) __hip_bfloat16 As[128 * 32];
  __shared__ __align__(16) __hip_bfloat16 Bs[128 * 32];

  const int tid = threadIdx.x;
  const int lane = tid & 63, wv = tid >> 6;

  // staging: 512 16B-chunks per matrix, 1 per thread each
  const int ra = tid >> 2;
  const int kc = ((tid & 3) ^ ((ra >> 1) & 3)) * 8;
  const int sa = base + ((m0 + ra < cnt) ? (m0 + ra) : (cnt - 1));
  const __hip_bfloat16* ga = xbf + (size_t)slot_token[sa] * ND + kc;
  const __hip_bfloat16* gb = wupT + ((size_t)e * NH + n0 + ra) * ND + kc;
  char* lA = (char*)As + tid * 16;
  char* lB = (char*)Bs + tid * 16;

  const int wm = (wv >> 2) * 64, wn = (wv & 3) * 32;
  const int l15 = lane & 15, q = lane >> 4;
  const int ssw = (q ^ ((l15 >> 1) & 3)) * 16;
  const char* rA = (const char*)As + (wm + l15) * 64 + ssw;
  const char* rB = (const char*)Bs + (wn + l15) * 64 + ssw;

  f32x4 acc[4][2] = {};

  for (int kk = 0; kk < ND; kk += 32) {
    __syncthreads();
    gl_lds16(ga + kk, lA);
    gl_lds16(gb + kk, lB);
    __syncthreads();
    short8 af[4], bfr[2];
#pragma unroll
    for (int i = 0; i < 4; ++i) af[i]  = *(const short8*)(rA + i * 1024);
#pragma unroll
    for (int i = 0; i < 2; ++i) bfr[i] = *(const short8*)(rB + i * 1024);
#pragma unroll
    for (int mt = 0; mt < 4; ++mt)
#pragma unroll
      for (int nt = 0; nt < 2; ++nt)
        acc[mt][nt] = __builtin_amdgcn_mfma_f32_16x16x32_bf16(af[mt], bfr[nt], acc[mt][nt], 0, 0, 0);
  }

#pragma unroll
  for (int mt = 0; mt < 4; ++mt) {
#pragma unroll
    for (int rr = 0; rr < 4; ++rr) {
      const int row = wm + mt * 16 + q * 4 + rr;
      if (row < valid) {
        const size_t rbase = (size_t)(base + m0 + row) * NH;
#pragma unroll
        for (int nt = 0; nt < 2; ++nt) {
          const int col = n0 + wn + nt * 16 + l15;
          const float v = acc[mt][nt][rr] + b_up[e * NH + col];
          hbuf[rbase + col] = __float2bfloat16(fast_gelu(v));
        }
      }
    }
  }
}

// ---------------- grouped GEMM 2: out = / += p * (H @ w_down + b_down) ----------------
__global__ __launch_bounds__(512, 5) void moe_gemm_down(
    const __hip_bfloat16* __restrict__ hbuf,
    const __hip_bfloat16* __restrict__ wdnT,   // [E][D][H]
    const float* __restrict__ b_down,
    const int* __restrict__ slot_token, const float* __restrict__ slot_p,
    const int* __restrict__ cnt_ek, const int* __restrict__ off_ek,
    const int* __restrict__ ntiles, const int* __restrict__ tl_dn,
    float* __restrict__ out, int kpos)
{
  if ((int)blockIdx.y >= ntiles[1 + kpos]) return;
  const int tl = tl_dn[kpos * 80 + blockIdx.y];
  const int e = tl >> 16, mb = tl & 0xffff;
  const int id = 2 * e + kpos;
  const int cnt = cnt_ek[id];
  const int base = off_ek[id];
  const int m0 = mb * 128;
  const int n0 = blockIdx.x * 128;
  const int valid = (cnt - m0 < 128) ? (cnt - m0) : 128;

  __shared__ __align__(16) __hip_bfloat16 As[128 * 32];
  __shared__ __align__(16) __hip_bfloat16 Bs[128 * 32];

  const int tid = threadIdx.x;
  const int lane = tid & 63, wv = tid >> 6;

  const int ra = tid >> 2;
  const int kc = ((tid & 3) ^ ((ra >> 1) & 3)) * 8;
  const int sa = base + ((m0 + ra < cnt) ? (m0 + ra) : (cnt - 1));
  const __hip_bfloat16* ga = hbuf + (size_t)sa * NH + kc;
  const __hip_bfloat16* gb = wdnT + ((size_t)e * ND + n0 + ra) * NH + kc;
  char* lA = (char*)As + tid * 16;
  char* lB = (char*)Bs + tid * 16;

  const int wm = (wv >> 2) * 64, wn = (wv & 3) * 32;
  const int l15 = lane & 15, q = lane >> 4;
  const int ssw = (q ^ ((l15 >> 1) & 3)) * 16;
  const char* rA = (const char*)As + (wm + l15) * 64 + ssw;
  const char* rB = (const char*)Bs + (wn + l15) * 64 + ssw;

  f32x4 acc[4][2] = {};

  for (int kk = 0; kk < NH; kk += 32) {
    __syncthreads();
    gl_lds16(ga + kk, lA);
    gl_lds16(gb + kk, lB);
    __syncthreads();
    short8 af[4], bfr[2];
#pragma unroll
    for (int i = 0; i < 4; ++i) af[i]  = *(const short8*)(rA + i * 1024);
#pragma unroll
    for (int i = 0; i < 2; ++i) bfr[i] = *(const short8*)(rB + i * 1024);
#pragma unroll
    for (int mt = 0; mt < 4; ++mt)
#pragma unroll
      for (int nt = 0; nt < 2; ++nt)
        acc[mt][nt] = __builtin_amdgcn_mfma_f32_16x16x32_bf16(af[mt], bfr[nt], acc[mt][nt], 0, 0, 0);
  }

#pragma unroll
  for (int mt = 0; mt < 4; ++mt) {
#pragma unroll
    for (int rr = 0; rr < 4; ++rr) {
      const int row = wm + mt * 16 + q * 4 + rr;
      if (row < valid) {
        const int slot = base + m0 + row;
        const int tok = slot_token[slot];
        const float p = slot_p[slot];
        const size_t obase = (size_t)tok * ND;
#pragma unroll
        for (int nt = 0; nt < 2; ++nt) {
          const int col = n0 + wn + nt * 16 + l15;
          const float v = (acc[mt][nt][rr] + b_down[e * ND + col]) * p;
          if (kpos == 0) out[obase + col] = v;
          else           out[obase + col] += v;
        }
      }
    }
  }
}

// ---------------- launch ----------------
extern "C" void kernel_launch(void* const* d_in, const int* in_sizes, int n_in,
                              void* d_out, int out_size, void* d_ws, size_t ws_size,
                              hipStream_t stream) {
  (void)in_sizes; (void)n_in; (void)out_size; (void)ws_size;
  const float* x   = (const float*)d_in[0];
  const float* rw  = (const float*)d_in[1];
  const float* rb  = (const float*)d_in[2];
  const float* wup = (const float*)d_in[3];
  const float* bup = (const float*)d_in[4];
  const float* wdn = (const float*)d_in[5];
  const float* bdn = (const float*)d_in[6];
  float* out = (float*)d_out;

  char* ws = (char*)d_ws;
  __hip_bfloat16* xbf  = (__hip_bfloat16*)(ws + O_XBF);
  __hip_bfloat16* wupT = (__hip_bfloat16*)(ws + O_WUPT);
  __hip_bfloat16* wdnT = (__hip_bfloat16*)(ws + O_WDNT);
  __hip_bfloat16* hbuf = (__hip_bfloat16*)(ws + O_HBUF);
  int*   slot_token = (int*)(ws + O_STOK);
  float* slot_p     = (float*)(ws + O_SP);
  int*   topk_e     = (int*)(ws + O_TKE);
  float* topk_p     = (float*)(ws + O_TKP);
  int*   cnt_ek  = (int*)(ws + O_CTRL);
  int*   fill_ek = (int*)(ws + O_CTRL + 64);
  float* probsum = (float*)(ws + O_CTRL + 128);
  int*   off_ek  = (int*)(ws + O_CTRL + 192);
  int*   ntiles  = (int*)(ws + O_CTRL + 256);
  int*   tl_up   = (int*)(ws + O_TLUP);
  int*   tl_dn   = (int*)(ws + O_TLDN);

  hipMemsetAsync(ws + O_CTRL, 0, 272, stream);

  // weight transposes (independent of router)
  moe_transpose_cast<<<dim3(NH / 64, ND / 64, NE), 256, 0, stream>>>(wup, wupT, ND, NH);
  moe_transpose_cast<<<dim3(ND / 64, NH / 64, NE), 256, 0, stream>>>(wdn, wdnT, NH, ND);

  // router (+ x->bf16), aux/offsets/tile-lists, scatter
  moe_router<<<256, 256, 0, stream>>>(x, rw, rb, xbf, out + (size_t)NT * ND + 1,
                                      topk_e, topk_p, cnt_ek, probsum);
  moe_finalize<<<1, 64, 0, stream>>>(cnt_ek, off_ek, probsum, out + (size_t)NT * ND,
                                     ntiles, tl_up, tl_dn);
  moe_scatter<<<NT / 256, 256, 0, stream>>>(topk_e, topk_p, off_ek, fill_ek, slot_token, slot_p);

  // grouped GEMMs (exact tile-list grids; blocks early-exit past device-side tile counts)
  moe_gemm_up<<<dim3(NH / 128, 144, 1), 512, 0, stream>>>(xbf, wupT, bup, slot_token,
                                                          cnt_ek, off_ek, ntiles, tl_up, hbuf);
  moe_gemm_down<<<dim3(ND / 128, 80, 1), 512, 0, stream>>>(hbuf, wdnT, bdn, slot_token, slot_p,
                                                           cnt_ek, off_ek, ntiles, tl_dn, out, 0);
  moe_gemm_down<<<dim3(ND / 128, 80, 1), 512, 0, stream>>>(hbuf, wdnT, bdn, slot_token, slot_p,
                                                           cnt_ek, off_ek, ntiles, tl_dn, out, 1);
}